// Round 4
// baseline (312.218 us; speedup 1.0000x reference)
//
#include <hip/hip_runtime.h>

// Problem constants (from reference): B=16, S=4096, H=768, NUM_WORDS=2048.
constexpr int B = 16;
constexpr int S = 4096;
constexpr int H = 768;
constexpr int NW = 2048;
constexpr int V4 = H / 4;               // 192 float4 per token row
constexpr int T = 32;                   // tokens per wave chunk
constexpr int CPS = 128;                // chunks per sample (128*32 >= S-2)
constexpr int WAVES_PER_BLK = 4;

__device__ __forceinline__ void acc4(float4& a, const float4 v) {
    a.x += v.x; a.y += v.y; a.z += v.z; a.w += v.w;
}

// One wave owns the 32-token chunk [t0, t0+32) and ALL words STARTING in it
// (reading past the chunk end for the rare crossing word). Tokens are
// processed through a 2-deep ping-pong pipeline of 8-token sub-blocks held
// in named registers: while sub-block k is consumed, sub-block k+1 is in
// flight, so each wave keeps 24-48 KB outstanding continuously (the one-shot
// round-3 design only had loads in flight ~half its lifetime).
__global__ __launch_bounds__(256)
void seg_mean_kernel(const float* __restrict__ hs,
                     const int* __restrict__ wid,
                     float* __restrict__ out) {
    const int wave = threadIdx.x >> 6;
    const int lane = threadIdx.x & 63;
    const int gc = blockIdx.x * WAVES_PER_BLK + wave;  // global chunk id
    const int b = gc >> 7;                             // / CPS
    const int chunk = gc & (CPS - 1);
    const int t0 = 1 + chunk * T;                      // tokens 0, S-1 sentinels

    const int* __restrict__ wrow = wid + (size_t)b * S;

    // wid gather FIRST (oldest outstanding -> its wait leaves token loads in
    // flight). Lanes 0..62: wid[t0-1+lane] (clamped); lane 63: maxw.
    int gidx = t0 - 1 + lane;
    if (gidx > S - 1) gidx = S - 1;
    if (lane == 63) gidx = S - 2;
    const int wv = wrow[gidx];

    const float4* __restrict__ base = (const float4*)(hs + (size_t)b * S * H);

#define SLOTS(X) X(0) X(1) X(2) X(3) X(4) X(5) X(6) X(7)
#define DECLP(J) float4 pA##J, pB##J, pC##J;
#define DECLQ(J) float4 qA##J, qB##J, qC##J;
    SLOTS(DECLP)
    SLOTS(DECLQ)

#define LOAD1(R, J, TB) { int t = (TB) + J; if (t > S - 2) t = S - 2;      \
        const float4* p = base + (size_t)t * V4;                           \
        R##A##J = p[lane]; R##B##J = p[lane + 64]; R##C##J = p[lane + 128]; }
#define ISSUE(R, TB) LOAD1(R,0,TB) LOAD1(R,1,TB) LOAD1(R,2,TB) LOAD1(R,3,TB) \
                     LOAD1(R,4,TB) LOAD1(R,5,TB) LOAD1(R,6,TB) LOAD1(R,7,TB)

    // prologue: two sub-blocks airborne
    ISSUE(p, t0)
    ISSUE(q, t0 + 8)
    __builtin_amdgcn_sched_barrier(0);

    const int maxw = __builtin_amdgcn_readlane(wv, 63);

    // boundary mask: bit l (1..62) => token (t0-1+l) differs from its
    // predecessor, i.e. token t0+J starts a word <=> bit (J+1) set.
    const int wprev = __shfl_up(wv, 1);
    const bool chg = (lane >= 1) && (lane <= 62) && (wv != wprev);
    const unsigned long long mask = __ballot(chg);

    const float4 z = make_float4(0.f, 0.f, 0.f, 0.f);
    float4 a0 = z, a1 = z, a2 = z;
    int cnt = 0, wcur = 0;
    bool active = false;

    auto flush = [&]() {
        const float inv = 1.0f / (float)cnt;
        float4 m0 = a0, m1 = a1, m2 = a2;
        m0.x *= inv; m0.y *= inv; m0.z *= inv; m0.w *= inv;
        m1.x *= inv; m1.y *= inv; m1.z *= inv; m1.w *= inv;
        m2.x *= inv; m2.y *= inv; m2.z *= inv; m2.w *= inv;
        float4* o = (float4*)(out + ((size_t)b * NW + wcur) * H);
        o[lane] = m0; o[lane + 64] = m1; o[lane + 128] = m2;
    };

#define STEPX(BIT, RA, RB, RC) {                                           \
        if ((mask >> (BIT)) & 1ull) {                                      \
            if (active) flush();                                           \
            const int wval = __builtin_amdgcn_readlane(wv, (BIT));         \
            active = (wval >= 0);                                          \
            if (active) { wcur = wval; a0 = z; a1 = z; a2 = z; cnt = 0; }  \
        }                                                                  \
        if (active) { acc4(a0, RA); acc4(a1, RB); acc4(a2, RC); ++cnt; } }
#define CONSUME(BB, R) \
    STEPX((BB)+1, R##A0, R##B0, R##C0) STEPX((BB)+2, R##A1, R##B1, R##C1)  \
    STEPX((BB)+3, R##A2, R##B2, R##C2) STEPX((BB)+4, R##A3, R##B3, R##C3)  \
    STEPX((BB)+5, R##A4, R##B4, R##C4) STEPX((BB)+6, R##A5, R##B5, R##C5)  \
    STEPX((BB)+7, R##A6, R##B6, R##C6) STEPX((BB)+8, R##A7, R##B7, R##C7)

    // steady state: consume one sub-block, refill its registers
    CONSUME(0, p)                 // tokens t0+0..7   (waits leave q in flight)
    ISSUE(p, t0 + 16)             // sub-block 2 into p
    __builtin_amdgcn_sched_barrier(0);
    CONSUME(8, q)                 // tokens t0+8..15
    ISSUE(q, t0 + 24)             // sub-block 3 into q
    __builtin_amdgcn_sched_barrier(0);
    CONSUME(16, p)                // tokens t0+16..23
    CONSUME(24, q)                // tokens t0+24..31
#undef CONSUME
#undef STEPX
#undef ISSUE
#undef LOAD1
#undef DECLP
#undef DECLQ
#undef SLOTS

    // extension: last owned word crosses the chunk end
    if (active) {
        int end;
        const unsigned long long hi = mask >> 33;  // tokens t0+32..t0+61
        if (hi) {
            end = t0 + 32 + __builtin_ctzll(hi);
        } else {
            end = t0 + 62;  // tokens t0+32..t0+61 confirmed same word
            while (true) {  // wid non-decreasing: first differing = word end
                int t = end + lane;
                if (t > S - 1) t = S - 1;
                const int wv2 = wrow[t];
                const unsigned long long m2 = __ballot(wv2 != wcur);
                if (m2) { end += __builtin_ctzll(m2); break; }
                end += 64;
            }
        }
        cnt += end - (t0 + 32);
        int t = t0 + 32;
        for (; t + 3 < end; t += 4) {  // 12 independent loads per iteration
            const float4* p0 = base + (size_t)t * V4;
            const float4* p1 = p0 + V4;
            const float4* p2 = p1 + V4;
            const float4* p3 = p2 + V4;
            float4 x00 = p0[lane], x01 = p0[lane + 64], x02 = p0[lane + 128];
            float4 x10 = p1[lane], x11 = p1[lane + 64], x12 = p1[lane + 128];
            float4 x20 = p2[lane], x21 = p2[lane + 64], x22 = p2[lane + 128];
            float4 x30 = p3[lane], x31 = p3[lane + 64], x32 = p3[lane + 128];
            acc4(a0, x00); acc4(a1, x01); acc4(a2, x02);
            acc4(a0, x10); acc4(a1, x11); acc4(a2, x12);
            acc4(a0, x20); acc4(a1, x21); acc4(a2, x22);
            acc4(a0, x30); acc4(a1, x31); acc4(a2, x32);
        }
        for (; t < end; ++t) {
            const float4* p = base + (size_t)t * V4;
            float4 v0 = p[lane], v1 = p[lane + 64], v2 = p[lane + 128];
            acc4(a0, v0); acc4(a1, v1); acc4(a2, v2);
        }
        flush();
    }

    // zero-duty: words w > maxw are never produced -> write zero rows.
    // 128 chunks x 16 words cover all 2048 word slots of this sample.
    {
        const int wz0 = chunk * 16;
#pragma unroll
        for (int k = 0; k < 16; ++k) {
            const int w = wz0 + k;
            if (w > maxw) {
                float4* o = (float4*)(out + ((size_t)b * NW + w) * H);
                o[lane] = z; o[lane + 64] = z; o[lane + 128] = z;
            }
        }
    }
}

extern "C" void kernel_launch(void* const* d_in, const int* in_sizes, int n_in,
                              void* d_out, int out_size, void* d_ws, size_t ws_size,
                              hipStream_t stream) {
    const float* hs = (const float*)d_in[0];
    const int* wid = (const int*)d_in[1];
    float* out = (float*)d_out;

    seg_mean_kernel<<<(B * CPS) / WAVES_PER_BLK, 64 * WAVES_PER_BLK, 0, stream>>>(
        hs, wid, out);
}